// Round 1
// baseline (101.876 us; speedup 1.0000x reference)
//
#include <hip/hip_runtime.h>

// Problem constants (from reference): B=8, L=2048, H=1024, C=64
#define PB 8
#define PL 2048
#define PH 1024
#define PC 64

// Kernel 1: s[b*L + l] = dot(feature[b,l,:], w)
// One wave per 4 consecutive rows. The per-lane w slice (16 floats as 4x float4,
// 16 VGPRs) is loaded ONCE per wave and reused across the 4 rows (4x less L1/L2
// traffic for w vs the 1-row-per-wave version). Feature loads stay perfectly
// coalesced: lane i reads row[j*256 + i*4 .. +3].
__global__ __launch_bounds__(256) void row_dot_kernel(
    const float* __restrict__ feature,   // [B*L, H]
    const float* __restrict__ w,         // [H]
    float* __restrict__ s)               // [B*L]
{
    const int gtid = blockIdx.x * 256 + threadIdx.x;
    const int wave = gtid >> 6;          // global wave id
    const int lane = threadIdx.x & 63;
    const int row0 = wave * 4;           // 4 rows per wave

    // w slice once per wave: 4x float4 = 16 VGPRs
    float4 wv[4];
#pragma unroll
    for (int j = 0; j < 4; ++j)
        wv[j] = *reinterpret_cast<const float4*>(w + j * 256 + lane * 4);

    float acc[4];
#pragma unroll
    for (int r = 0; r < 4; ++r) {
        const float* rp = feature + (size_t)(row0 + r) * PH;
        float a = 0.0f;
#pragma unroll
        for (int j = 0; j < 4; ++j) {
            float4 f = *reinterpret_cast<const float4*>(rp + j * 256 + lane * 4);
            a += f.x * wv[j].x + f.y * wv[j].y + f.z * wv[j].z + f.w * wv[j].w;
        }
        acc[r] = a;
    }

    // wave64 butterfly reduce, 4 rows
#pragma unroll
    for (int r = 0; r < 4; ++r)
#pragma unroll
        for (int off = 32; off > 0; off >>= 1)
            acc[r] += __shfl_down(acc[r], off, 64);

    if (lane == 0)   // row0 is a multiple of 4 -> 16B-aligned float4 store
        *reinterpret_cast<float4*>(s + row0) =
            make_float4(acc[0], acc[1], acc[2], acc[3]);
}

// Kernel 2: per (b,c) span, mean of s[b, src..end] + bias.
// One wave per span (B*C = 512 spans). Aligned float4 loads over the span with
// per-element predication at the edges: trip count drops from ceil(len/64)
// scalar loads (<=32) to ceil(len/256) float4 loads (<=8) -- this loop is
// latency-bound on L2/L3 hits, so 4x fewer serialized iterations.
__global__ __launch_bounds__(256) void span_pool_kernel(
    const float* __restrict__ s,         // [B, L]
    const int* __restrict__ pos,         // [B, C, 2] (src, end) inclusive
    const float* __restrict__ bias,      // [1]
    float* __restrict__ out)             // [B*C]
{
    const int gtid = blockIdx.x * 256 + threadIdx.x;
    const int span = gtid >> 6;          // 0..B*C-1
    const int lane = threadIdx.x & 63;

    const int b   = span >> 6;           // PC = 64
    const int src = pos[span * 2 + 0];
    const int end = pos[span * 2 + 1];

    const float* sb = s + b * PL;

    // Start at src rounded down to a multiple of 4 (16B-aligned, in-bounds:
    // l0 <= end <= 2047 and l0 % 4 == 0 => l0 <= 2044 => l0+3 <= 2047).
    float acc = 0.0f;
    for (int l0 = (src & ~3) + lane * 4; l0 <= end; l0 += 256) {
        float4 v = *reinterpret_cast<const float4*>(sb + l0);
        acc += (l0 + 0 >= src)               ? v.x : 0.0f;  // l0 <= end by loop cond
        acc += (l0 + 1 >= src && l0 + 1 <= end) ? v.y : 0.0f;
        acc += (l0 + 2 >= src && l0 + 2 <= end) ? v.z : 0.0f;
        acc += (l0 + 3 >= src && l0 + 3 <= end) ? v.w : 0.0f;
    }

#pragma unroll
    for (int off = 32; off > 0; off >>= 1)
        acc += __shfl_down(acc, off, 64);

    if (lane == 0) {
        const float cnt = (float)(end - src + 1);  // src<=end guaranteed, cnt>=1
        out[span] = acc / cnt + bias[0];
    }
}

extern "C" void kernel_launch(void* const* d_in, const int* in_sizes, int n_in,
                              void* d_out, int out_size, void* d_ws, size_t ws_size,
                              hipStream_t stream) {
    const float* feature = (const float*)d_in[0];   // [B, L, H] fp32
    const float* fc_w    = (const float*)d_in[1];   // [1, H]
    const float* fc_b    = (const float*)d_in[2];   // [1]
    const int*   pos     = (const int*)d_in[3];     // [B, C, 2] int32
    float*       out     = (float*)d_out;           // [B*C, 1] fp32
    float*       s       = (float*)d_ws;            // B*L floats = 64 KB scratch

    // Kernel 1: B*L = 16384 rows, 4 rows/wave -> 4096 waves -> 1024 blocks
    row_dot_kernel<<<(PB * PL) / 16, 256, 0, stream>>>(feature, fc_w, s);

    // Kernel 2: B*C = 512 spans, 1 wave/span -> 128 blocks
    span_pool_kernel<<<(PB * PC * 64) / 256, 256, 0, stream>>>(s, pos, fc_b, out);
}